// Round 11
// baseline (843.375 us; speedup 1.0000x reference)
//
#include <hip/hip_runtime.h>
#include <hip/hip_bf16.h>

#define NNODES 100000
#define NEDGES 1600000
#define NRELS 16
#define NBASES 8
#define DFEAT 128
#define NCLS 40
#define MAXDEG 64
#define KG 1024     // bf16 g-part K
#define KR 128      // bf16 root-part K
#define NBUCK 16
#define BSHIFT 13   // dst>>13 -> buckets 0..12 live
#define BCAP 163840 // per-bucket edge capacity (expected ~131k)
#define BPB 160     // blocks per bucket in k_scat (1024 edges/block)

typedef __attribute__((ext_vector_type(8))) short bf16x8v;
typedef __attribute__((ext_vector_type(4))) float f32x4v;
typedef __attribute__((ext_vector_type(2))) float f32x2v;

struct __align__(8) bf16x4s { __hip_bfloat162 lo, hi; };

// Fused fp32->bf16 convert + per-row int8 quant (wave per row).
__global__ __launch_bounds__(256)
void k_cvq(const float* __restrict__ x, __hip_bfloat16* __restrict__ xb,
           short* __restrict__ q8, float* __restrict__ qs, int nrows)
{
    int wave = threadIdx.x >> 6, lane = threadIdx.x & 63;
    int v = blockIdx.x * 4 + wave;
    if (v >= nrows) return;
    float2 xv = ((const float2*)x)[(size_t)v * 64 + lane];
    __hip_bfloat162 bv;
    bv.x = __float2bfloat16(xv.x);
    bv.y = __float2bfloat16(xv.y);
    ((__hip_bfloat162*)xb)[(size_t)v * 64 + lane] = bv;
    float m = fmaxf(fabsf(xv.x), fabsf(xv.y));
#pragma unroll
    for (int o = 32; o; o >>= 1) m = fmaxf(m, __shfl_xor(m, o));
    float inv = (m > 0.f) ? 127.f / m : 0.f;
    int qx = (int)rintf(xv.x * inv), qy = (int)rintf(xv.y * inv);
    q8[(size_t)v * 64 + lane] = (short)((qx & 0xff) | (qy << 8));
    if (lane == 0) qs[v] = m * (1.f / 127.f);
}

// Pass 1: bin edges by dst-range with LDS-aggregated dense appends.
__global__ __launch_bounds__(256)
void k_bin(const int* __restrict__ esrc, const int* __restrict__ edst,
           const int* __restrict__ etyp,
           uint2* __restrict__ bins, unsigned* __restrict__ gcount)
{
    __shared__ unsigned hist[NBUCK], gbase[NBUCK];
    int tid = threadIdx.x;
    if (tid < NBUCK) hist[tid] = 0u;
    __syncthreads();
    int e = blockIdx.x * 256 + tid;
    bool val = (e < NEDGES);
    int b = 0; unsigned rank = 0; uint2 rec = {0u, 0u};
    if (val) {
        int d = edst[e];
        b = d >> BSHIFT;
        rec.x = ((unsigned)esrc[e] << 4) | (unsigned)etyp[e];
        rec.y = (unsigned)d;
        rank = atomicAdd(&hist[b], 1u);
    }
    __syncthreads();
    if (tid < NBUCK) gbase[tid] = atomicAdd(&gcount[tid], hist[tid]);
    __syncthreads();
    if (val) {
        unsigned pos = gbase[b] + rank;
        if (pos < BCAP) bins[(size_t)b * BCAP + pos] = rec;
    }
}

// Pass 2: bucket-major scatter; each bucket's ELL slice (2 MB) is L2-resident
// so partial lines merge in L2 instead of thrashing to HBM.
__global__ __launch_bounds__(256)
void k_scat(const uint2* __restrict__ bins, const unsigned* __restrict__ gcount,
            unsigned* __restrict__ degD, unsigned* __restrict__ ell)
{
    int bkt = blockIdx.x / BPB;
    int blk = blockIdx.x % BPB;
    unsigned cnt = gcount[bkt];
    if (cnt > BCAP) cnt = BCAP;
    unsigned base = (unsigned)blk * 1024u;
    if (base >= cnt) return;
    const uint2* bp = bins + (size_t)bkt * BCAP;
#pragma unroll
    for (int i = 0; i < 4; i++) {
        unsigned idx = base + i * 256 + threadIdx.x;
        if (idx < cnt) {
            uint2 r = bp[idx];
            unsigned slot = atomicAdd(&degD[r.y], 1u);
            if (slot < MAXDEG) ell[(size_t)r.y * MAXDEG + slot] = r.x;
        }
    }
}

// Per-row int8 quantization of node features (layers 1,2 gather source).
__global__ __launch_bounds__(256)
void k_quant(const __hip_bfloat16* __restrict__ h,
             short* __restrict__ q8, float* __restrict__ qs, int nrows)
{
    int wave = threadIdx.x >> 6, lane = threadIdx.x & 63;
    int v = blockIdx.x * 4 + wave;
    if (v >= nrows) return;
    __hip_bfloat162 xv = ((const __hip_bfloat162*)h)[(size_t)v * 64 + lane];
    float xl = __bfloat162float(xv.x), xh = __bfloat162float(xv.y);
    float m = fmaxf(fabsf(xl), fabsf(xh));
#pragma unroll
    for (int o = 32; o; o >>= 1) m = fmaxf(m, __shfl_xor(m, o));
    float inv = (m > 0.f) ? 127.f / m : 0.f;
    int qx = (int)rintf(xl * inv), qy = (int)rintf(xh * inv);
    q8[(size_t)v * 64 + lane] = (short)((qx & 0xff) | (qy << 8));
    if (lane == 0) qs[v] = m * (1.f / 127.f);
}

// Two nodes per wave, 16-deep gather pipeline, folded coefficients via LDS
// broadcast. Emits the g-part only, bf16 (2048 B/row); root handled by
// k_gemm phase 2 straight from hin.
__global__ __launch_bounds__(256)
void k_agg(const short* __restrict__ q8, const float* __restrict__ qs,
           const unsigned* __restrict__ ell,
           const unsigned* __restrict__ degD,
           const float* __restrict__ comp,
           __hip_bfloat16* __restrict__ A,
           int r0, int rows)
{
    __shared__ float compS[NRELS * NBASES];
    __shared__ __align__(16) float cS[8][MAXDEG][8];
    __shared__ unsigned sS[8][MAXDEG];
    __shared__ unsigned histS[8][NRELS];
    if (threadIdx.x < NRELS * NBASES) compS[threadIdx.x] = comp[threadIdx.x];
    __syncthreads();

    int wave = threadIdx.x >> 6, lane = threadIdx.x & 63;
    int half = lane >> 5, hl = lane & 31;
    int node = wave * 2 + half;
    int rl = blockIdx.x * 8 + node;
    bool alive = (rl < rows);
    int v = alive ? (r0 + rl) : 0;
    int ne = alive ? (int)degD[v] : 0; if (ne > MAXDEG) ne = MAXDEG;

    if (alive) {
        const unsigned* erow = ell + (size_t)v * MAXDEG;
        unsigned p0 = (hl < ne) ? erow[hl] : 0u;
        unsigned p1 = (hl + 32 < ne) ? erow[hl + 32] : 0u;
        if (hl < NRELS) histS[node][hl] = 0u;
        if (hl < ne)      atomicAdd(&histS[node][p0 & 15u], 1u);
        if (hl + 32 < ne) atomicAdd(&histS[node][p1 & 15u], 1u);
#pragma unroll
        for (int r = 0; r < 2; r++) {
            unsigned p = r ? p1 : p0;
            int slot = hl + 32 * r;
            bool vl = (slot < ne);
            unsigned t = p & 15u;
            int s = vl ? (int)(p >> 4) : 0;
            unsigned cnt = vl ? histS[node][t] : 1u;
            if (cnt < 1u) cnt = 1u;
            float w = vl ? (qs[s] / (float)cnt) : 0.f;
            f32x4v c0, c1;
#pragma unroll
            for (int b = 0; b < 4; b++) c0[b] = compS[t * NBASES + b] * w;
#pragma unroll
            for (int b = 0; b < 4; b++) c1[b] = compS[t * NBASES + 4 + b] * w;
            *(f32x4v*)&cS[node][slot][0] = c0;
            *(f32x4v*)&cS[node][slot][4] = c1;
            sS[node][slot] = (unsigned)s;
        }
    }

    f32x2v accA[NBASES], accB[NBASES];
#pragma unroll
    for (int b = 0; b < NBASES; b++) { accA[b] = (f32x2v){0.f,0.f}; accB[b] = (f32x2v){0.f,0.f}; }

    if (alive) {
        for (int e0 = 0; e0 < ne; e0 += 16) {
            unsigned qd[16];
#pragma unroll
            for (int j = 0; j < 16; j++) {
                unsigned s = sS[node][e0 + j];
                qd[j] = ((const unsigned*)(q8 + (size_t)s * 64))[hl];
            }
#pragma unroll
            for (int j = 0; j < 16; j++) {
                f32x4v ca = *(const f32x4v*)&cS[node][e0 + j][0];
                f32x4v cb = *(const f32x4v*)&cS[node][e0 + j][4];
                unsigned d = qd[j];
                f32x2v f01, f23;
                f01.x = (float)(char)(d & 0xff);
                f01.y = (float)(char)((d >> 8) & 0xff);
                f23.x = (float)(char)((d >> 16) & 0xff);
                f23.y = (float)(char)(d >> 24);
                accA[0] += ca[0] * f01;  accB[0] += ca[0] * f23;
                accA[1] += ca[1] * f01;  accB[1] += ca[1] * f23;
                accA[2] += ca[2] * f01;  accB[2] += ca[2] * f23;
                accA[3] += ca[3] * f01;  accB[3] += ca[3] * f23;
                accA[4] += cb[0] * f01;  accB[4] += cb[0] * f23;
                accA[5] += cb[1] * f01;  accB[5] += cb[1] * f23;
                accA[6] += cb[2] * f01;  accB[6] += cb[2] * f23;
                accA[7] += cb[3] * f01;  accB[7] += cb[3] * f23;
            }
        }
        __hip_bfloat16* Arow = A + (size_t)rl * KG;
#pragma unroll
        for (int b = 0; b < NBASES; b++) {
            bf16x4s o;
            o.lo.x = __float2bfloat16(accA[b].x);
            o.lo.y = __float2bfloat16(accA[b].y);
            o.hi.x = __float2bfloat16(accB[b].x);
            o.hi.y = __float2bfloat16(accB[b].y);
            *(bf16x4s*)&Arow[b * 128 + 4 * hl] = o;
        }
    }
}

// Weights bf16: WTb[o][k<1024] (bases, K-contig) + WTr[o][0..127] (root).
__global__ __launch_bounds__(256)
void k_w(const float* __restrict__ bases, const float* __restrict__ root,
         __hip_bfloat16* __restrict__ WTb, __hip_bfloat16* __restrict__ WTr,
         int dout, int npad)
{
    int idx = blockIdx.x * 256 + threadIdx.x;
    int total = npad * (KG + KR);
    if (idx >= total) return;
    int o = idx / (KG + KR), k = idx - o * (KG + KR);
    float v = 0.f;
    if (o < dout) v = (k < KG) ? bases[(size_t)k * dout + o]
                               : root[(size_t)(k - KG) * dout + o];
    if (k < KG) WTb[(size_t)o * KG + k] = __float2bfloat16(v);
    else        WTr[(size_t)o * KR + (k - KG)] = __float2bfloat16(v);
}

// Hybrid-source GEMM, all bf16: phase 1 K=1024 over A(g)/WTb, phase 2 K=128
// root straight from hin/WTr, one shared f32 accumulator (same summation
// order as the R8 single-matrix version -> identical numerics).
template<int NT, bool RELU, bool FINAL>
__global__ __launch_bounds__(256)
void k_gemm(const __hip_bfloat16* __restrict__ A,
            const __hip_bfloat16* __restrict__ WTb,
            const __hip_bfloat16* __restrict__ hin,
            const __hip_bfloat16* __restrict__ WTr,
            const float* __restrict__ bias,
            void* __restrict__ outp,
            int r0, int rows, int dout)
{
    constexpr int WM = (NT == 128) ? 2 : 4;
    constexpr int WN = 4 / WM;
    constexpr int MT = 128 / (16 * WM);
    constexpr int NTW = NT / (16 * WN);
    __shared__ __align__(16) __hip_bfloat16 As[128 * 32];
    __shared__ __align__(16) __hip_bfloat16 Bs[NT * 32];
    int tid = threadIdx.x;
    int wave = tid >> 6, lane = tid & 63;
    int wm = wave % WM, wn = wave / WM;
    int bm = blockIdx.x * 128;
    int lm = lane & 15, lq = lane >> 4;
    f32x4v acc[MT][NTW];
#pragma unroll
    for (int a = 0; a < MT; a++)
#pragma unroll
        for (int b = 0; b < NTW; b++) acc[a][b] = (f32x4v){0.f,0.f,0.f,0.f};

    for (int k0 = 0; k0 < KG; k0 += 32) {              // ---- phase 1: g-part
#pragma unroll
        for (int j = 0; j < 2; j++) {
            int slot = tid + 256 * j;
            int row = slot >> 2, kc = (slot & 3) << 3;
            __builtin_amdgcn_global_load_lds(
                (const __attribute__((address_space(1))) void*)
                    &A[(size_t)(bm + row) * KG + k0 + kc],
                (__attribute__((address_space(3))) void*)&As[slot * 8],
                16, 0, 0);
        }
#pragma unroll
        for (int j = 0; j < NT / 64; j++) {
            int slot = tid + 256 * j;
            int row = slot >> 2, kc = (slot & 3) << 3;
            __builtin_amdgcn_global_load_lds(
                (const __attribute__((address_space(1))) void*)
                    &WTb[(size_t)row * KG + k0 + kc],
                (__attribute__((address_space(3))) void*)&Bs[slot * 8],
                16, 0, 0);
        }
        __syncthreads();
        bf16x8v af[MT], bfr[NTW];
#pragma unroll
        for (int mt = 0; mt < MT; mt++)
            af[mt] = *(const bf16x8v*)&As[(wm * (16 * MT) + mt * 16 + lm) * 32 + lq * 8];
#pragma unroll
        for (int nt = 0; nt < NTW; nt++)
            bfr[nt] = *(const bf16x8v*)&Bs[(wn * (16 * NTW) + nt * 16 + lm) * 32 + lq * 8];
#pragma unroll
        for (int mt = 0; mt < MT; mt++)
#pragma unroll
            for (int nt = 0; nt < NTW; nt++)
                acc[mt][nt] = __builtin_amdgcn_mfma_f32_16x16x32_bf16(
                    af[mt], bfr[nt], acc[mt][nt], 0, 0, 0);
        __syncthreads();
    }

    for (int kk = 0; kk < KR; kk += 32) {              // ---- phase 2: root
#pragma unroll
        for (int j = 0; j < 2; j++) {
            int slot = tid + 256 * j;
            int row = slot >> 2, kc = (slot & 3) << 3;
            __builtin_amdgcn_global_load_lds(
                (const __attribute__((address_space(1))) void*)
                    &hin[(size_t)(r0 + bm + row) * KR + kk + kc],
                (__attribute__((address_space(3))) void*)&As[slot * 8],
                16, 0, 0);
        }
#pragma unroll
        for (int j = 0; j < NT / 64; j++) {
            int slot = tid + 256 * j;
            int row = slot >> 2, kc = (slot & 3) << 3;
            __builtin_amdgcn_global_load_lds(
                (const __attribute__((address_space(1))) void*)
                    &WTr[(size_t)row * KR + kk + kc],
                (__attribute__((address_space(3))) void*)&Bs[slot * 8],
                16, 0, 0);
        }
        __syncthreads();
        bf16x8v af[MT], bfr[NTW];
#pragma unroll
        for (int mt = 0; mt < MT; mt++)
            af[mt] = *(const bf16x8v*)&As[(wm * (16 * MT) + mt * 16 + lm) * 32 + lq * 8];
#pragma unroll
        for (int nt = 0; nt < NTW; nt++)
            bfr[nt] = *(const bf16x8v*)&Bs[(wn * (16 * NTW) + nt * 16 + lm) * 32 + lq * 8];
#pragma unroll
        for (int mt = 0; mt < MT; mt++)
#pragma unroll
            for (int nt = 0; nt < NTW; nt++)
                acc[mt][nt] = __builtin_amdgcn_mfma_f32_16x16x32_bf16(
                    af[mt], bfr[nt], acc[mt][nt], 0, 0, 0);
        __syncthreads();
    }

#pragma unroll
    for (int mt = 0; mt < MT; mt++) {
        int rbase = bm + wm * (16 * MT) + mt * 16 + lq * 4;
#pragma unroll
        for (int nt = 0; nt < NTW; nt++) {
            int col = wn * (16 * NTW) + nt * 16 + lm;
            float bc = bias[col < dout ? col : 0];
#pragma unroll
            for (int i = 0; i < 4; i++) {
                int rl = rbase + i;
                if (rl < rows && col < dout) {
                    float v = acc[mt][nt][i] + bc;
                    if (RELU) v = fmaxf(v, 0.f);
                    if (FINAL)
                        ((float*)outp)[(size_t)(r0 + rl) * NCLS + col] = v;
                    else
                        ((__hip_bfloat16*)outp)[(size_t)(r0 + rl) * DFEAT + col] =
                            __float2bfloat16(v);
                }
            }
        }
    }
}

extern "C" void kernel_launch(void* const* d_in, const int* in_sizes, int n_in,
                              void* d_out, int out_size, void* d_ws, size_t ws_size,
                              hipStream_t stream)
{
    const float* x  = (const float*)d_in[0];
    const int* esrc = (const int*)d_in[1];
    const int* edst = (const int*)d_in[2];
    const int* etyp = (const int*)d_in[3];
    const float* basesA[3] = {(const float*)d_in[4], (const float*)d_in[8], (const float*)d_in[12]};
    const float* compA[3]  = {(const float*)d_in[5], (const float*)d_in[9], (const float*)d_in[13]};
    const float* rootA[3]  = {(const float*)d_in[6], (const float*)d_in[10], (const float*)d_in[14]};
    const float* biasA[3]  = {(const float*)d_in[7], (const float*)d_in[11], (const float*)d_in[15]};

    size_t off = 0;
    char* base = (char*)d_ws;
    auto carve = [&](size_t bytes) -> void* {
        void* r = base + off;
        off += (bytes + 255) & ~(size_t)255;
        return r;
    };
    __hip_bfloat16* xb = (__hip_bfloat16*)carve((size_t)NNODES * DFEAT * 2);
    __hip_bfloat16* h1 = (__hip_bfloat16*)carve((size_t)NNODES * DFEAT * 2);
    __hip_bfloat16* WTb = (__hip_bfloat16*)carve((size_t)128 * KG * 2);
    __hip_bfloat16* WTr = (__hip_bfloat16*)carve((size_t)128 * KR * 2);
    unsigned* ell    = (unsigned*)carve((size_t)NNODES * MAXDEG * 4);
    unsigned* degD   = (unsigned*)carve((size_t)NNODES * 4);
    unsigned* gcount = (unsigned*)carve(NBUCK * 4);
    short* q8  = (short*)carve((size_t)NNODES * 64 * 2);
    float* qsc = (float*)carve((size_t)NNODES * 4);
    __hip_bfloat16* h2 = xb;   // xb dead after layer 1 -> alias

    if (ws_size <= off) return;
    size_t abytes = ws_size - off;
    // bins alias the A region: bins are dead after k_scat, before first k_agg
    uint2* bins = (uint2*)(base + off);
    if (abytes < (size_t)NBUCK * BCAP * 8) return;
    size_t arows = abytes / ((size_t)KG * 2);
    if (arows > 100096) arows = 100096;
    int chunk = (int)(arows & ~(size_t)127);
    if (chunk < 128) return;
    __hip_bfloat16* A = (__hip_bfloat16*)(base + off);

    (void)hipMemsetAsync(degD, 0, (size_t)NNODES * 4, stream);
    (void)hipMemsetAsync(gcount, 0, NBUCK * 4, stream);
    k_cvq<<<(NNODES + 3) / 4, 256, 0, stream>>>(x, xb, q8, qsc, NNODES);
    k_bin<<<(NEDGES + 255) / 256, 256, 0, stream>>>(esrc, edst, etyp, bins, gcount);
    k_scat<<<NBUCK * BPB, 256, 0, stream>>>(bins, gcount, degD, ell);

    const __hip_bfloat16* hin = xb;
    __hip_bfloat16* houts[2] = {h1, h2};
    for (int l = 0; l < 3; l++) {
        int dout = (l == 2) ? NCLS : DFEAT;
        int npad = (l == 2) ? 64 : 128;
        if (l > 0)
            k_quant<<<(NNODES + 3) / 4, 256, 0, stream>>>(hin, q8, qsc, NNODES);
        k_w<<<(npad * (KG + KR) + 255) / 256, 256, 0, stream>>>(basesA[l], rootA[l], WTb, WTr, dout, npad);
        for (int r0 = 0; r0 < NNODES; r0 += chunk) {
            int rows = NNODES - r0; if (rows > chunk) rows = chunk;
            k_agg<<<(rows + 7) / 8, 256, 0, stream>>>(q8, qsc, ell, degD, compA[l], A, r0, rows);
            int gm = (rows + 127) / 128;
            if (l < 2)
                k_gemm<128, true, false><<<gm, 256, 0, stream>>>(A, WTb, hin, WTr, biasA[l], houts[l], r0, rows, dout);
            else
                k_gemm<64, false, true><<<gm, 256, 0, stream>>>(A, WTb, hin, WTr, biasA[l], d_out, r0, rows, dout);
        }
        if (l < 2) hin = houts[l];
    }
}